// Round 1
// baseline (10387.650 us; speedup 1.0000x reference)
//
#include <hip/hip_runtime.h>
#include <stdint.h>
#include <math.h>

// ---------------------------------------------------------------------------
// StoryJudger2: word branch (2x LSTM H=1000) + paragraph branch (2x biLSTM)
// B=8, S=256, V=50257, E=512, P=768, H=1000.
//
// Strategy:
//  - Input projections xg = A @ Wih^T + b as bf16 MFMA GEMMs (f32 out).
//  - Recurrent scans: persistent kernel, Whh register-resident as MFMA
//    B-fragments; per-step global h broadcast + custom device barrier.
//  - para reverse layer-1 only needs step 0 (h0=c0=0) -> closed form in final.
// ---------------------------------------------------------------------------

typedef __attribute__((ext_vector_type(8))) short short8;
typedef __attribute__((ext_vector_type(4))) float f32x4;
typedef __attribute__((ext_vector_type(4))) unsigned int u32x4;

#define BB 8
#define SS 256
#define MM (BB*SS)     // 2048 token rows
#define HH 1000
#define GG 4000        // 4*H gate dim
#define NP 4096        // padded gate dim (GEMM N)
#define HP 1024        // padded hidden dim (K for recurrent mfma)

__device__ __forceinline__ unsigned short f2bf(float f){
  unsigned u = __builtin_bit_cast(unsigned, f);
  unsigned r = u + 0x7fffu + ((u >> 16) & 1u);     // RNE
  return (unsigned short)(r >> 16);
}
__device__ __forceinline__ float bf2f(unsigned short s){
  unsigned u = ((unsigned)s) << 16;
  return __builtin_bit_cast(float, u);
}
__device__ __forceinline__ float sigf(float x){ return 1.0f / (1.0f + expf(-x)); }

__device__ __forceinline__ void async_copy16(const void* g, void* l){
  // global -> LDS, 16B per lane; LDS dest = wave-uniform base + lane*16.
  __builtin_amdgcn_global_load_lds(
      (const __attribute__((address_space(1))) unsigned int*)g,
      (__attribute__((address_space(3))) unsigned int*)l, 16, 0, 0);
}

// ---------------------------------------------------------------- prep ------
__global__ void kzero(unsigned int* __restrict__ p, size_t nwords){
  size_t stride = (size_t)gridDim.x * blockDim.x;
  for (size_t i = (size_t)blockIdx.x*blockDim.x + threadIdx.x; i < nwords; i += stride)
    p[i] = 0u;
}

// src [4000][K] f32 -> dst [4096][Kpad] bf16, zero-padded
__global__ void kpadw(const float* __restrict__ src, unsigned short* __restrict__ dst,
                      int K, int Kpad){
  size_t total = (size_t)NP * Kpad;
  size_t stride = (size_t)gridDim.x * blockDim.x;
  for (size_t i = (size_t)blockIdx.x*blockDim.x + threadIdx.x; i < total; i += stride){
    int nrow = (int)(i / Kpad);
    int k    = (int)(i % Kpad);
    float v = (nrow < GG && k < K) ? src[(size_t)nrow*K + k] : 0.0f;
    dst[i] = f2bf(v);
  }
}

// dst[m][e] = bf16(emb[x[m]][e]), m = b*256+s
__global__ void kgather(const float* __restrict__ emb, const int* __restrict__ x,
                        unsigned short* __restrict__ dst, int E){
  size_t total = (size_t)MM * E;
  size_t stride = (size_t)gridDim.x * blockDim.x;
  for (size_t i = (size_t)blockIdx.x*blockDim.x + threadIdx.x; i < total; i += stride){
    size_t m = i / E, e = i % E;
    dst[i] = f2bf(emb[(size_t)x[m]*E + e]);
  }
}

// ---------------------------------------------------------------- GEMM ------
// out[m][n] = sum_k A[m][k]*W[n][k] + bias[n]; A [2048][Kpad] bf16,
// W [4096][Kpad] bf16, out [2048][4000] f32. Grid = 16 (m) x 32 (n) tiles.
__launch_bounds__(256, 2)
__global__ void kgemm(const unsigned short* __restrict__ A,
                      const unsigned short* __restrict__ W,
                      const float* __restrict__ bias,
                      float* __restrict__ out, int Kpad){
  __shared__ __align__(16) unsigned short ldsA[128*64];
  __shared__ __align__(16) unsigned short ldsB[128*64];
  const int tid = threadIdx.x;
  const int w = tid >> 6, l = tid & 63;
  const int wr = w >> 1, wc = w & 1;
  const int tm = blockIdx.x & 15, tn = blockIdx.x >> 4;
  const size_t Kb = (size_t)Kpad * 2;
  const int nk = Kpad >> 6;

  f32x4 acc[4][4];
#pragma unroll
  for (int a = 0; a < 4; ++a)
#pragma unroll
    for (int b = 0; b < 4; ++b) acc[a][b] = (f32x4){0.f,0.f,0.f,0.f};

  for (int kt = 0; kt < nk; ++kt){
    // stage A,B tiles (128x64 bf16 each) -- linear LDS dest, inverse-swizzled
    // global source so that swizzled ds_read below is conflict-free (rule #21).
#pragma unroll
    for (int c = 0; c < 4; ++c){
      const int chunk = c*4 + w;            // wave-uniform
      const int flat = chunk*1024 + l*16;   // byte within tile
      const int row = flat >> 7;
      const int off = flat & 127;
      const int soff = off ^ ((row & 7) << 4);
      async_copy16((const char*)A + (size_t)(tm*128+row)*Kb + (size_t)kt*128 + soff,
                   (char*)ldsA + chunk*1024);
      async_copy16((const char*)W + (size_t)(tn*128+row)*Kb + (size_t)kt*128 + soff,
                   (char*)ldsB + chunk*1024);
    }
    asm volatile("s_waitcnt vmcnt(0)" ::: "memory");
    __syncthreads();

#pragma unroll
    for (int ks = 0; ks < 2; ++ks){
      short8 af[4], bf[4];
#pragma unroll
      for (int mf = 0; mf < 4; ++mf){
        const int row = wr*64 + mf*16 + (l & 15);
        const int off = ((ks*32 + (l>>4)*8)*2) ^ ((row & 7) << 4);
        af[mf] = *(const short8*)((const char*)ldsA + row*128 + off);
      }
#pragma unroll
      for (int nf = 0; nf < 4; ++nf){
        const int row = wc*64 + nf*16 + (l & 15);
        const int off = ((ks*32 + (l>>4)*8)*2) ^ ((row & 7) << 4);
        bf[nf] = *(const short8*)((const char*)ldsB + row*128 + off);
      }
#pragma unroll
      for (int mf = 0; mf < 4; ++mf)
#pragma unroll
        for (int nf = 0; nf < 4; ++nf)
          acc[mf][nf] = __builtin_amdgcn_mfma_f32_16x16x32_bf16(
              af[mf], bf[nf], acc[mf][nf], 0, 0, 0);
    }
    __syncthreads();
  }

  // epilogue: C layout col = lane&15, row = (lane>>4)*4 + q  [m89/m91]
#pragma unroll
  for (int nf = 0; nf < 4; ++nf){
    const int n = tn*128 + wc*64 + nf*16 + (l & 15);
    if (n < GG){
      const float bv = bias[n];
#pragma unroll
      for (int mf = 0; mf < 4; ++mf){
#pragma unroll
        for (int q = 0; q < 4; ++q){
          const int m = tm*128 + wr*64 + mf*16 + (l>>4)*4 + q;
          out[(size_t)m*GG + n] = acc[mf][nf][q] + bv;
        }
      }
    }
  }
}

// ---------------------------------------------------------------- scan ------
struct LstmDesc {
  const float* xg;          // [2048][4000] f32 (bias included)
  const float* whh;         // [4000][1000] f32
  unsigned short* hbuf;     // bf16 h sequence buffer (also feedback source)
  int hstride;              // row stride in elems (1024 or 2048)
  int joff;                 // column offset in hbuf
  int rev;                  // reversed scan
};
struct ScanArgs {
  LstmDesc d[3];
  unsigned int* bar;        // [256] per-step counters, pre-zeroed
  int nwg;
};

// 63 WGs per LSTM; each wave owns 4 hidden units x 4 gates (16 MFMA cols),
// Whh slice lives in 128 VGPRs of B-fragments for all 256 steps.
__launch_bounds__(256, 1)
__global__ void kscan(ScanArgs args){
  __shared__ __align__(16) unsigned short h_lds[8*HP];  // swizzled [8][1024] bf16
  __shared__ float ex[4][128];                          // per-wave gate exchange
  const int tid = threadIdx.x;
  const int wv = tid >> 6, l = tid & 63;
  const int lstm = blockIdx.x / 63, slice = blockIdx.x % 63;
  const LstmDesc D = args.d[lstm];

  const int col = l & 15, g4 = l >> 4;
  const int gate = col >> 2, jl = col & 3;
  const int j = slice*16 + wv*4 + jl;          // hidden unit for this mfma col
  const int n = gate*HH + j;                   // gate-column in [0,4000)
  const bool jv = (j < HH);

  // ---- one-time: load Whh B-fragments (lane holds B[k][col]=Whh[n][k]) ----
  short8 wf[32];
#pragma unroll
  for (int ks = 0; ks < 32; ++ks){
    short8 v = (short8){0,0,0,0,0,0,0,0};
    const int kb = ks*32 + g4*8;
    if (jv && kb < HH){
      const float* s = D.whh + (size_t)n*HH + kb;
#pragma unroll
      for (int i = 0; i < 8; ++i) v[i] = (short)f2bf(s[i]);
    }
    wf[ks] = v;
  }

  const int arow = l & 15;                     // A-fragment batch row
  const bool av = arow < 8;
  const int aswz = (arow & 7) << 4;
  float c_reg = 0.f;                           // cell state (lanes 0..31)
  const int ub = l & 7, ujl = (l >> 3) & 3;
  const int uj = slice*16 + wv*4 + ujl;

  for (int t = 0; t < SS; ++t){
    const int pos  = D.rev ? (SS-1 - t) : t;
    const int ppos = D.rev ? (pos + 1) : (pos - 1);

    // xg prefetch (f32, bias included) for this lane's 4 batch rows
    float xgv[4] = {0.f,0.f,0.f,0.f};
    if (g4 < 2 && jv){
#pragma unroll
      for (int q = 0; q < 4; ++q){
        const int b = g4*4 + q;
        xgv[q] = D.xg[(size_t)(b*SS + pos)*GG + n];
      }
    }

    // stage h_prev (8 x 1024 bf16) into LDS, XOR-swizzled rows
    if (t == 0){
#pragma unroll
      for (int cc = 0; cc < 4; ++cc){
        const int f16 = cc*256 + tid;
        *(u32x4*)((char*)h_lds + f16*16) = (u32x4){0u,0u,0u,0u};
      }
    } else {
#pragma unroll
      for (int cc = 0; cc < 4; ++cc){
        const int f16 = cc*256 + tid;
        const int fb = f16*16;
        const int hr = fb >> 11;               // batch row 0..7
        const int off = fb & 2047;
        const char* src = (const char*)D.hbuf
            + ((size_t)(hr*SS + ppos)*D.hstride + D.joff)*2 + off;
        const u32x4 v = *(const u32x4*)src;
        *(u32x4*)((char*)h_lds + hr*2048 + (off ^ ((hr & 7) << 4))) = v;
      }
    }
    __syncthreads();

    // gates = h_prev @ Whh^T  (K=1024, 32 chained mfmas into one f32x4)
    f32x4 acc = (f32x4){0.f,0.f,0.f,0.f};
#pragma unroll
    for (int ks = 0; ks < 32; ++ks){
      const int off = ((ks*64) | (g4*16)) ^ aswz;
      short8 a = av ? *(const short8*)((const char*)h_lds + arow*2048 + off)
                    : (short8){0,0,0,0,0,0,0,0};
      acc = __builtin_amdgcn_mfma_f32_16x16x32_bf16(a, wf[ks], acc, 0, 0, 0);
    }

    // exchange i/f/g/o within wave (C rows = batch, valid rows 0..7)
    if (g4 < 2){
#pragma unroll
      for (int q = 0; q < 4; ++q)
        ex[wv][(jl*4 + gate)*8 + (g4*4 + q)] = acc[q] + xgv[q];
    }
    __syncthreads();

    if (l < 32){
      const float iv = ex[wv][(ujl*4 + 0)*8 + ub];
      const float fv = ex[wv][(ujl*4 + 1)*8 + ub];
      const float gv = ex[wv][(ujl*4 + 2)*8 + ub];
      const float ov = ex[wv][(ujl*4 + 3)*8 + ub];
      c_reg = sigf(fv)*c_reg + sigf(iv)*tanhf(gv);
      const float h = sigf(ov)*tanhf(c_reg);
      if (uj < HH)
        D.hbuf[(size_t)(ub*SS + pos)*D.hstride + D.joff + uj] = f2bf(h);
    }
    __syncthreads();

    // device-scope barrier: fresh counter per step (no reset races)
    if (tid == 0){
      __threadfence();                          // release h stores agent-wide
      atomicAdd(&args.bar[t], 1u);
      while (__hip_atomic_load(&args.bar[t], __ATOMIC_RELAXED,
                               __HIP_MEMORY_SCOPE_AGENT) < (unsigned)args.nwg){
        __builtin_amdgcn_s_sleep(1);
      }
    }
    __syncthreads();
    __threadfence();                            // invalidate caches before reads
  }
}

// --------------------------------------------------------------- final ------
__global__ void kfinal(const unsigned short* __restrict__ hw1,
                       const unsigned short* __restrict__ hpf1,
                       const float* __restrict__ xgr1,
                       const float* __restrict__ w1, const float* __restrict__ b1,
                       const float* __restrict__ w2, const float* __restrict__ b2,
                       const float* __restrict__ wc, const float* __restrict__ bc,
                       float* __restrict__ out){
  __shared__ float red[256];
  const int tid = threadIdx.x;
  for (int b = 0; b < BB; ++b){
    const size_t r = (size_t)(b*SS + (SS-1));
    float ps = 0.f, wsm = 0.f;
    for (int j = tid; j < HH; j += 256){
      ps  += bf2f(hpf1[r*1024 + j]) * w2[j];
      // para reverse layer-1, step 0 (h0=c0=0): closed form from xg
      const float iv = xgr1[r*GG + j];
      const float gv = xgr1[r*GG + 2000 + j];
      const float ov = xgr1[r*GG + 3000 + j];
      const float cc = sigf(iv)*tanhf(gv);
      ps  += sigf(ov)*tanhf(cc) * w2[HH + j];
      wsm += bf2f(hw1[r*1024 + j]) * w1[j];
    }
    red[tid] = ps; __syncthreads();
    for (int s = 128; s > 0; s >>= 1){ if (tid < s) red[tid] += red[tid+s]; __syncthreads(); }
    const float PS = red[0]; __syncthreads();
    red[tid] = wsm; __syncthreads();
    for (int s = 128; s > 0; s >>= 1){ if (tid < s) red[tid] += red[tid+s]; __syncthreads(); }
    const float WS = red[0]; __syncthreads();
    if (tid == 0)
      out[b] = wc[0]*(PS + b2[0]) + wc[1]*(WS + b1[0]) + bc[0];
    __syncthreads();
  }
}

// --------------------------------------------------------------- host -------
extern "C" void kernel_launch(void* const* d_in, const int* in_sizes, int n_in,
                              void* d_out, int out_size, void* d_ws, size_t ws_size,
                              hipStream_t stream){
  const int*   x      = (const int*)  d_in[0];
  const float* embw   = (const float*)d_in[1];
  const float* embp   = (const float*)d_in[2];
  const float* l1Wih0 = (const float*)d_in[3];
  const float* l1Whh0 = (const float*)d_in[4];
  const float* l1b0   = (const float*)d_in[5];
  const float* l1Wih1 = (const float*)d_in[6];
  const float* l1Whh1 = (const float*)d_in[7];
  const float* l1b1   = (const float*)d_in[8];
  const float* f0Wih  = (const float*)d_in[9];
  const float* f0Whh  = (const float*)d_in[10];
  const float* f0b    = (const float*)d_in[11];
  const float* r0Wih  = (const float*)d_in[12];
  const float* r0Whh  = (const float*)d_in[13];
  const float* r0b    = (const float*)d_in[14];
  const float* f1Wih  = (const float*)d_in[15];
  const float* f1Whh  = (const float*)d_in[16];
  const float* f1b    = (const float*)d_in[17];
  const float* r1Wih  = (const float*)d_in[18];
  const float* r1Whh  = (const float*)d_in[19];
  const float* r1b    = (const float*)d_in[20];
  const float* w1     = (const float*)d_in[21];
  const float* b1     = (const float*)d_in[22];
  const float* w2     = (const float*)d_in[23];
  const float* b2     = (const float*)d_in[24];
  const float* wc     = (const float*)d_in[25];
  const float* bc     = (const float*)d_in[26];
  float* out = (float*)d_out;
  (void)in_sizes; (void)n_in; (void)out_size; (void)ws_size;

  char* ws = (char*)d_ws;
  size_t off = 0;
  auto alloc = [&](size_t bytes)->char*{
    char* p = ws + off;
    off += (bytes + 255) & ~(size_t)255;
    return p;
  };
  // padded bf16 Wih copies [4096][Kpad]
  unsigned short* pw_l1Wih0 = (unsigned short*)alloc((size_t)NP*512*2);
  unsigned short* pw_f0Wih  = (unsigned short*)alloc((size_t)NP*768*2);
  unsigned short* pw_r0Wih  = (unsigned short*)alloc((size_t)NP*768*2);
  unsigned short* pw_l1Wih1 = (unsigned short*)alloc((size_t)NP*1024*2);
  unsigned short* pw_f1Wih  = (unsigned short*)alloc((size_t)NP*2048*2);
  unsigned short* pw_r1Wih  = (unsigned short*)alloc((size_t)NP*2048*2);
  // gathered embeddings (bf16)
  unsigned short* a_w = (unsigned short*)alloc((size_t)MM*512*2);
  unsigned short* a_p = (unsigned short*)alloc((size_t)MM*768*2);
  // gate pre-activations (f32), reused across the two layers
  float* xg0 = (float*)alloc((size_t)MM*GG*4);
  float* xg1 = (float*)alloc((size_t)MM*GG*4);
  float* xg2 = (float*)alloc((size_t)MM*GG*4);
  // h sequence buffers (bf16) + barrier counters -- contiguous, zeroed per call
  char* zbase = ws + off;
  unsigned short* h_w0  = (unsigned short*)alloc((size_t)MM*1024*2);
  unsigned short* cat0  = (unsigned short*)alloc((size_t)MM*2048*2); // [fwd|rev|pad]
  unsigned short* h_w1  = (unsigned short*)alloc((size_t)MM*1024*2);
  unsigned short* h_pf1 = (unsigned short*)alloc((size_t)MM*1024*2);
  unsigned int* barB = (unsigned int*)alloc(256*4);
  unsigned int* barD = (unsigned int*)alloc(256*4);
  size_t zwords = (size_t)((ws + off) - zbase) / 4;

  kzero<<<dim3(1024), dim3(256), 0, stream>>>((unsigned int*)zbase, zwords);
  kpadw<<<dim3(1024), dim3(256), 0, stream>>>(l1Wih0, pw_l1Wih0, 512, 512);
  kpadw<<<dim3(1024), dim3(256), 0, stream>>>(f0Wih,  pw_f0Wih,  768, 768);
  kpadw<<<dim3(1024), dim3(256), 0, stream>>>(r0Wih,  pw_r0Wih,  768, 768);
  kpadw<<<dim3(1024), dim3(256), 0, stream>>>(l1Wih1, pw_l1Wih1, 1000, 1024);
  kpadw<<<dim3(1024), dim3(256), 0, stream>>>(f1Wih,  pw_f1Wih,  2000, 2048);
  kpadw<<<dim3(1024), dim3(256), 0, stream>>>(r1Wih,  pw_r1Wih,  2000, 2048);
  kgather<<<dim3(512), dim3(256), 0, stream>>>(embw, x, a_w, 512);
  kgather<<<dim3(512), dim3(256), 0, stream>>>(embp, x, a_p, 768);

  // layer-0 projections
  kgemm<<<dim3(512), dim3(256), 0, stream>>>(a_w, pw_l1Wih0, l1b0, xg0, 512);
  kgemm<<<dim3(512), dim3(256), 0, stream>>>(a_p, pw_f0Wih,  f0b,  xg1, 768);
  kgemm<<<dim3(512), dim3(256), 0, stream>>>(a_p, pw_r0Wih,  r0b,  xg2, 768);

  // layer-0 scans: word fwd, para fwd, para rev (rev writes cat0 cols 1000..)
  {
    ScanArgs sa;
    sa.d[0] = LstmDesc{xg0, l1Whh0, h_w0, 1024, 0, 0};
    sa.d[1] = LstmDesc{xg1, f0Whh,  cat0, 2048, 0, 0};
    sa.d[2] = LstmDesc{xg2, r0Whh,  cat0, 2048, 1000, 1};
    sa.bar = barB; sa.nwg = 189;
    kscan<<<dim3(189), dim3(256), 0, stream>>>(sa);
  }

  // layer-1 projections (A = layer-0 h sequences)
  kgemm<<<dim3(512), dim3(256), 0, stream>>>(h_w0, pw_l1Wih1, l1b1, xg0, 1024);
  kgemm<<<dim3(512), dim3(256), 0, stream>>>(cat0, pw_f1Wih,  f1b,  xg1, 2048);
  kgemm<<<dim3(512), dim3(256), 0, stream>>>(cat0, pw_r1Wih,  r1b,  xg2, 2048);

  // layer-1 scans: word fwd + para fwd (para rev needs only step 0 -> kfinal)
  {
    ScanArgs sa;
    sa.d[0] = LstmDesc{xg0, l1Whh1, h_w1,  1024, 0, 0};
    sa.d[1] = LstmDesc{xg1, f1Whh,  h_pf1, 1024, 0, 0};
    sa.d[2] = LstmDesc{nullptr, nullptr, nullptr, 1024, 0, 0};
    sa.bar = barD; sa.nwg = 126;
    kscan<<<dim3(126), dim3(256), 0, stream>>>(sa);
  }

  kfinal<<<dim3(1), dim3(256), 0, stream>>>(h_w1, h_pf1, xg2,
                                            w1, b1, w2, b2, wc, bc, out);
}

// Round 2
// 3185.293 us; speedup vs baseline: 3.2611x; 3.2611x over previous
//
#include <hip/hip_runtime.h>
#include <stdint.h>
#include <math.h>

// ---------------------------------------------------------------------------
// StoryJudger2: word branch (2x LSTM H=1000) + paragraph branch (2x biLSTM)
// B=8, S=256, V=50257, E=512, P=768, H=1000.
//
// Strategy:
//  - Input projections xg = A @ Wih^T + b as bf16 MFMA GEMMs (f32 out).
//  - Recurrent scans: persistent kernel, Whh register-resident as MFMA
//    B-fragments; per-step h broadcast via RELAXED AGENT-SCOPE atomics
//    (write-through to Infinity Cache; no threadfence / L2 wb+inv) and a
//    per-LSTM device barrier (63 WGs each).
//  - para reverse layer-1 only needs step 0 (h0=c0=0) -> closed form in final.
// ---------------------------------------------------------------------------

typedef __attribute__((ext_vector_type(8))) short short8;
typedef __attribute__((ext_vector_type(4))) float f32x4;
typedef __attribute__((ext_vector_type(4))) unsigned int u32x4;

#define BB 8
#define SS 256
#define MM (BB*SS)     // 2048 token rows
#define HH 1000
#define GG 4000        // 4*H gate dim
#define NP 4096        // padded gate dim (GEMM N)
#define HP 1024        // padded hidden dim (K for recurrent mfma)

__device__ __forceinline__ unsigned short f2bf(float f){
  unsigned u = __builtin_bit_cast(unsigned, f);
  unsigned r = u + 0x7fffu + ((u >> 16) & 1u);     // RNE
  return (unsigned short)(r >> 16);
}
__device__ __forceinline__ float bf2f(unsigned short s){
  unsigned u = ((unsigned)s) << 16;
  return __builtin_bit_cast(float, u);
}
__device__ __forceinline__ float sigf(float x){ return 1.0f / (1.0f + expf(-x)); }

__device__ __forceinline__ void async_copy16(const void* g, void* l){
  // global -> LDS, 16B per lane; LDS dest = wave-uniform base + lane*16.
  __builtin_amdgcn_global_load_lds(
      (const __attribute__((address_space(1))) unsigned int*)g,
      (__attribute__((address_space(3))) unsigned int*)l, 16, 0, 0);
}

// ---------------------------------------------------------------- prep ------
__global__ void kzero(unsigned int* __restrict__ p, size_t nwords){
  size_t stride = (size_t)gridDim.x * blockDim.x;
  for (size_t i = (size_t)blockIdx.x*blockDim.x + threadIdx.x; i < nwords; i += stride)
    p[i] = 0u;
}

// src [4000][K] f32 -> dst [4096][Kpad] bf16, zero-padded
__global__ void kpadw(const float* __restrict__ src, unsigned short* __restrict__ dst,
                      int K, int Kpad){
  size_t total = (size_t)NP * Kpad;
  size_t stride = (size_t)gridDim.x * blockDim.x;
  for (size_t i = (size_t)blockIdx.x*blockDim.x + threadIdx.x; i < total; i += stride){
    int nrow = (int)(i / Kpad);
    int k    = (int)(i % Kpad);
    float v = (nrow < GG && k < K) ? src[(size_t)nrow*K + k] : 0.0f;
    dst[i] = f2bf(v);
  }
}

// dst[m][e] = bf16(emb[x[m]][e]), m = b*256+s
__global__ void kgather(const float* __restrict__ emb, const int* __restrict__ x,
                        unsigned short* __restrict__ dst, int E){
  size_t total = (size_t)MM * E;
  size_t stride = (size_t)gridDim.x * blockDim.x;
  for (size_t i = (size_t)blockIdx.x*blockDim.x + threadIdx.x; i < total; i += stride){
    size_t m = i / E, e = i % E;
    dst[i] = f2bf(emb[(size_t)x[m]*E + e]);
  }
}

// ---------------------------------------------------------------- GEMM ------
// out[m][n] = sum_k A[m][k]*W[n][k] + bias[n]; A [2048][Kpad] bf16,
// W [4096][Kpad] bf16, out [2048][4000] f32. Grid = 16 (m) x 32 (n) tiles.
__launch_bounds__(256, 2)
__global__ void kgemm(const unsigned short* __restrict__ A,
                      const unsigned short* __restrict__ W,
                      const float* __restrict__ bias,
                      float* __restrict__ out, int Kpad){
  __shared__ __align__(16) unsigned short ldsA[128*64];
  __shared__ __align__(16) unsigned short ldsB[128*64];
  const int tid = threadIdx.x;
  const int w = tid >> 6, l = tid & 63;
  const int wr = w >> 1, wc = w & 1;
  const int tm = blockIdx.x & 15, tn = blockIdx.x >> 4;
  const size_t Kb = (size_t)Kpad * 2;
  const int nk = Kpad >> 6;

  f32x4 acc[4][4];
#pragma unroll
  for (int a = 0; a < 4; ++a)
#pragma unroll
    for (int b = 0; b < 4; ++b) acc[a][b] = (f32x4){0.f,0.f,0.f,0.f};

  for (int kt = 0; kt < nk; ++kt){
    // stage A,B tiles (128x64 bf16 each) -- linear LDS dest, inverse-swizzled
    // global source so that swizzled ds_read below is conflict-free (rule #21).
#pragma unroll
    for (int c = 0; c < 4; ++c){
      const int chunk = c*4 + w;            // wave-uniform
      const int flat = chunk*1024 + l*16;   // byte within tile
      const int row = flat >> 7;
      const int off = flat & 127;
      const int soff = off ^ ((row & 7) << 4);
      async_copy16((const char*)A + (size_t)(tm*128+row)*Kb + (size_t)kt*128 + soff,
                   (char*)ldsA + chunk*1024);
      async_copy16((const char*)W + (size_t)(tn*128+row)*Kb + (size_t)kt*128 + soff,
                   (char*)ldsB + chunk*1024);
    }
    asm volatile("s_waitcnt vmcnt(0)" ::: "memory");
    __syncthreads();

#pragma unroll
    for (int ks = 0; ks < 2; ++ks){
      short8 af[4], bf[4];
#pragma unroll
      for (int mf = 0; mf < 4; ++mf){
        const int row = wr*64 + mf*16 + (l & 15);
        const int off = ((ks*32 + (l>>4)*8)*2) ^ ((row & 7) << 4);
        af[mf] = *(const short8*)((const char*)ldsA + row*128 + off);
      }
#pragma unroll
      for (int nf = 0; nf < 4; ++nf){
        const int row = wc*64 + nf*16 + (l & 15);
        const int off = ((ks*32 + (l>>4)*8)*2) ^ ((row & 7) << 4);
        bf[nf] = *(const short8*)((const char*)ldsB + row*128 + off);
      }
#pragma unroll
      for (int mf = 0; mf < 4; ++mf)
#pragma unroll
        for (int nf = 0; nf < 4; ++nf)
          acc[mf][nf] = __builtin_amdgcn_mfma_f32_16x16x32_bf16(
              af[mf], bf[nf], acc[mf][nf], 0, 0, 0);
    }
    __syncthreads();
  }

  // epilogue: C layout col = lane&15, row = (lane>>4)*4 + q  [m89/m91]
#pragma unroll
  for (int nf = 0; nf < 4; ++nf){
    const int n = tn*128 + wc*64 + nf*16 + (l & 15);
    if (n < GG){
      const float bv = bias[n];
#pragma unroll
      for (int mf = 0; mf < 4; ++mf){
#pragma unroll
        for (int q = 0; q < 4; ++q){
          const int m = tm*128 + wr*64 + mf*16 + (l>>4)*4 + q;
          out[(size_t)m*GG + n] = acc[mf][nf][q] + bv;
        }
      }
    }
  }
}

// ---------------------------------------------------------------- scan ------
struct LstmDesc {
  const float* xg;          // [2048][4000] f32 (bias included)
  const float* whh;         // [4000][1000] f32
  unsigned short* hbuf;     // bf16 h sequence buffer (also feedback source)
  int hstride;              // row stride in elems (1024 or 2048)
  int joff;                 // column offset in hbuf
  int rev;                  // reversed scan
};
struct ScanArgs {
  LstmDesc d[3];
  unsigned int* bar;        // [n_lstm][256] per-step counters, pre-zeroed
};

// 63 WGs per LSTM; each wave owns 4 hidden units x 4 gates (16 MFMA cols),
// Whh slice lives in registers as MFMA B-fragments for all 256 steps.
// Cross-WG h exchange: relaxed agent-scope atomics (write-through to the
// coherence point), per-LSTM barrier -- NO cache-wide fences anywhere.
__launch_bounds__(256, 1)
__global__ void kscan(ScanArgs args){
  __shared__ __align__(16) unsigned short h_lds[8*HP];  // swizzled [8][1024] bf16
  __shared__ float ex[4][128];                          // per-wave gate exchange
  const int tid = threadIdx.x;
  const int wv = tid >> 6, l = tid & 63;
  const int lstm = blockIdx.x / 63, slice = blockIdx.x % 63;
  const LstmDesc D = args.d[lstm];
  unsigned int* bar = args.bar + lstm * SS;

  const int col = l & 15, g4 = l >> 4;
  const int gate = col >> 2, jl = col & 3;
  const int j = slice*16 + wv*4 + jl;          // hidden unit for this mfma col
  const int n = gate*HH + j;                   // gate-column in [0,4000)
  const bool jv = (j < HH);

  // ---- one-time: load Whh B-fragments (lane holds B[k][col]=Whh[n][k]) ----
  short8 wf[32];
#pragma unroll
  for (int ks = 0; ks < 32; ++ks){
    short8 v = (short8){0,0,0,0,0,0,0,0};
    const int kb = ks*32 + g4*8;
    if (jv && kb < HH){
      const float* s = D.whh + (size_t)n*HH + kb;
#pragma unroll
      for (int i = 0; i < 8; ++i) v[i] = (short)f2bf(s[i]);
    }
    wf[ks] = v;
  }

  const int arow = l & 15;                     // A-fragment batch row
  const bool av = arow < 8;
  const int aswz = (arow & 7) << 4;
  float c_reg = 0.f;                           // cell state (lanes 0..31)
  const int ub = l & 7, ujl = (l >> 3) & 3;
  const int uj = slice*16 + wv*4 + ujl;

  for (int t = 0; t < SS; ++t){
    const int pos  = D.rev ? (SS-1 - t) : t;
    const int ppos = D.rev ? (pos + 1) : (pos - 1);

    // xg prefetch (f32, bias included) for this lane's 4 batch rows.
    // Normal cached loads: xg is read-only during the scan, L2 stays warm
    // because we never invalidate.
    float xgv[4] = {0.f,0.f,0.f,0.f};
    if (g4 < 2 && jv){
#pragma unroll
      for (int q = 0; q < 4; ++q){
        const int b = g4*4 + q;
        xgv[q] = D.xg[(size_t)(b*SS + pos)*GG + n];
      }
    }

    // stage h_prev (8 x 1024 bf16) into LDS, XOR-swizzled rows.
    // Loads are relaxed agent-scope atomics (8B) -> bypass L1/L2, read the
    // coherence point directly; no acquire fence needed.
    if (t == 0){
#pragma unroll
      for (int cc = 0; cc < 4; ++cc){
        const int f16 = cc*256 + tid;
        *(u32x4*)((char*)h_lds + f16*16) = (u32x4){0u,0u,0u,0u};
      }
    } else {
#pragma unroll
      for (int cc = 0; cc < 8; ++cc){
        const int f8 = cc*256 + tid;
        const int fb = f8*8;                   // byte offset in 16KB h block
        const int hr = fb >> 11;               // batch row 0..7
        const int off = fb & 2047;
        const unsigned long long* src = (const unsigned long long*)
            ((const char*)D.hbuf + ((size_t)(hr*SS + ppos)*D.hstride + D.joff)*2 + off);
        const unsigned long long v =
            __hip_atomic_load(src, __ATOMIC_RELAXED, __HIP_MEMORY_SCOPE_AGENT);
        *(unsigned long long*)((char*)h_lds + hr*2048 + (off ^ ((hr & 7) << 4))) = v;
      }
    }
    __syncthreads();

    // gates = h_prev @ Whh^T  (K=1024, 32 chained mfmas into one f32x4)
    f32x4 acc = (f32x4){0.f,0.f,0.f,0.f};
#pragma unroll
    for (int ks = 0; ks < 32; ++ks){
      const int off = ((ks*64) | (g4*16)) ^ aswz;
      short8 a = av ? *(const short8*)((const char*)h_lds + arow*2048 + off)
                    : (short8){0,0,0,0,0,0,0,0};
      acc = __builtin_amdgcn_mfma_f32_16x16x32_bf16(a, wf[ks], acc, 0, 0, 0);
    }

    // exchange i/f/g/o within wave (C rows = batch, valid rows 0..7)
    if (g4 < 2){
#pragma unroll
      for (int q = 0; q < 4; ++q)
        ex[wv][(jl*4 + gate)*8 + (g4*4 + q)] = acc[q] + xgv[q];
    }
    __syncthreads();

    if (l < 32){
      const float iv = ex[wv][(ujl*4 + 0)*8 + ub];
      const float fv = ex[wv][(ujl*4 + 1)*8 + ub];
      const float gv = ex[wv][(ujl*4 + 2)*8 + ub];
      const float ov = ex[wv][(ujl*4 + 3)*8 + ub];
      c_reg = sigf(fv)*c_reg + sigf(iv)*tanhf(gv);
      const float h = sigf(ov)*tanhf(c_reg);
      if (uj < HH)
        __hip_atomic_store(&D.hbuf[(size_t)(ub*SS + pos)*D.hstride + D.joff + uj],
                           f2bf(h), __ATOMIC_RELAXED, __HIP_MEMORY_SCOPE_AGENT);
    }
    // __syncthreads drains vmcnt(0) for EVERY wave (compiler emits full
    // s_waitcnt before s_barrier), so all write-through h stores are at the
    // coherence point before tid 0 signals arrival.
    __syncthreads();

    if (tid == 0){
      __hip_atomic_fetch_add(&bar[t], 1u, __ATOMIC_RELAXED, __HIP_MEMORY_SCOPE_AGENT);
      while (__hip_atomic_load(&bar[t], __ATOMIC_RELAXED,
                               __HIP_MEMORY_SCOPE_AGENT) < 63u){
        __builtin_amdgcn_s_sleep(1);
      }
    }
    __syncthreads();
    asm volatile("" ::: "memory");   // keep next-step h loads below the spin
  }
}

// --------------------------------------------------------------- final ------
__global__ void kfinal(const unsigned short* __restrict__ hw1,
                       const unsigned short* __restrict__ hpf1,
                       const float* __restrict__ xgr1,
                       const float* __restrict__ w1, const float* __restrict__ b1,
                       const float* __restrict__ w2, const float* __restrict__ b2,
                       const float* __restrict__ wc, const float* __restrict__ bc,
                       float* __restrict__ out){
  __shared__ float red[256];
  const int tid = threadIdx.x;
  for (int b = 0; b < BB; ++b){
    const size_t r = (size_t)(b*SS + (SS-1));
    float ps = 0.f, wsm = 0.f;
    for (int j = tid; j < HH; j += 256){
      ps  += bf2f(hpf1[r*1024 + j]) * w2[j];
      // para reverse layer-1, step 0 (h0=c0=0): closed form from xg
      const float iv = xgr1[r*GG + j];
      const float gv = xgr1[r*GG + 2000 + j];
      const float ov = xgr1[r*GG + 3000 + j];
      const float cc = sigf(iv)*tanhf(gv);
      ps  += sigf(ov)*tanhf(cc) * w2[HH + j];
      wsm += bf2f(hw1[r*1024 + j]) * w1[j];
    }
    red[tid] = ps; __syncthreads();
    for (int s = 128; s > 0; s >>= 1){ if (tid < s) red[tid] += red[tid+s]; __syncthreads(); }
    const float PS = red[0]; __syncthreads();
    red[tid] = wsm; __syncthreads();
    for (int s = 128; s > 0; s >>= 1){ if (tid < s) red[tid] += red[tid+s]; __syncthreads(); }
    const float WS = red[0]; __syncthreads();
    if (tid == 0)
      out[b] = wc[0]*(PS + b2[0]) + wc[1]*(WS + b1[0]) + bc[0];
    __syncthreads();
  }
}

// --------------------------------------------------------------- host -------
extern "C" void kernel_launch(void* const* d_in, const int* in_sizes, int n_in,
                              void* d_out, int out_size, void* d_ws, size_t ws_size,
                              hipStream_t stream){
  const int*   x      = (const int*)  d_in[0];
  const float* embw   = (const float*)d_in[1];
  const float* embp   = (const float*)d_in[2];
  const float* l1Wih0 = (const float*)d_in[3];
  const float* l1Whh0 = (const float*)d_in[4];
  const float* l1b0   = (const float*)d_in[5];
  const float* l1Wih1 = (const float*)d_in[6];
  const float* l1Whh1 = (const float*)d_in[7];
  const float* l1b1   = (const float*)d_in[8];
  const float* f0Wih  = (const float*)d_in[9];
  const float* f0Whh  = (const float*)d_in[10];
  const float* f0b    = (const float*)d_in[11];
  const float* r0Wih  = (const float*)d_in[12];
  const float* r0Whh  = (const float*)d_in[13];
  const float* r0b    = (const float*)d_in[14];
  const float* f1Wih  = (const float*)d_in[15];
  const float* f1Whh  = (const float*)d_in[16];
  const float* f1b    = (const float*)d_in[17];
  const float* r1Wih  = (const float*)d_in[18];
  const float* r1Whh  = (const float*)d_in[19];
  const float* r1b    = (const float*)d_in[20];
  const float* w1     = (const float*)d_in[21];
  const float* b1     = (const float*)d_in[22];
  const float* w2     = (const float*)d_in[23];
  const float* b2     = (const float*)d_in[24];
  const float* wc     = (const float*)d_in[25];
  const float* bc     = (const float*)d_in[26];
  float* out = (float*)d_out;
  (void)in_sizes; (void)n_in; (void)out_size; (void)ws_size;

  char* ws = (char*)d_ws;
  size_t off = 0;
  auto alloc = [&](size_t bytes)->char*{
    char* p = ws + off;
    off += (bytes + 255) & ~(size_t)255;
    return p;
  };
  // padded bf16 Wih copies [4096][Kpad]
  unsigned short* pw_l1Wih0 = (unsigned short*)alloc((size_t)NP*512*2);
  unsigned short* pw_f0Wih  = (unsigned short*)alloc((size_t)NP*768*2);
  unsigned short* pw_r0Wih  = (unsigned short*)alloc((size_t)NP*768*2);
  unsigned short* pw_l1Wih1 = (unsigned short*)alloc((size_t)NP*1024*2);
  unsigned short* pw_f1Wih  = (unsigned short*)alloc((size_t)NP*2048*2);
  unsigned short* pw_r1Wih  = (unsigned short*)alloc((size_t)NP*2048*2);
  // gathered embeddings (bf16)
  unsigned short* a_w = (unsigned short*)alloc((size_t)MM*512*2);
  unsigned short* a_p = (unsigned short*)alloc((size_t)MM*768*2);
  // gate pre-activations (f32), reused across the two layers
  float* xg0 = (float*)alloc((size_t)MM*GG*4);
  float* xg1 = (float*)alloc((size_t)MM*GG*4);
  float* xg2 = (float*)alloc((size_t)MM*GG*4);
  // h sequence buffers (bf16) + barrier counters -- contiguous, zeroed per call
  char* zbase = ws + off;
  unsigned short* h_w0  = (unsigned short*)alloc((size_t)MM*1024*2);
  unsigned short* cat0  = (unsigned short*)alloc((size_t)MM*2048*2); // [fwd|rev|pad]
  unsigned short* h_w1  = (unsigned short*)alloc((size_t)MM*1024*2);
  unsigned short* h_pf1 = (unsigned short*)alloc((size_t)MM*1024*2);
  unsigned int* barB = (unsigned int*)alloc(3*256*4);
  unsigned int* barD = (unsigned int*)alloc(3*256*4);
  size_t zwords = (size_t)((ws + off) - zbase) / 4;

  kzero<<<dim3(1024), dim3(256), 0, stream>>>((unsigned int*)zbase, zwords);
  kpadw<<<dim3(1024), dim3(256), 0, stream>>>(l1Wih0, pw_l1Wih0, 512, 512);
  kpadw<<<dim3(1024), dim3(256), 0, stream>>>(f0Wih,  pw_f0Wih,  768, 768);
  kpadw<<<dim3(1024), dim3(256), 0, stream>>>(r0Wih,  pw_r0Wih,  768, 768);
  kpadw<<<dim3(1024), dim3(256), 0, stream>>>(l1Wih1, pw_l1Wih1, 1000, 1024);
  kpadw<<<dim3(1024), dim3(256), 0, stream>>>(f1Wih,  pw_f1Wih,  2000, 2048);
  kpadw<<<dim3(1024), dim3(256), 0, stream>>>(r1Wih,  pw_r1Wih,  2000, 2048);
  kgather<<<dim3(512), dim3(256), 0, stream>>>(embw, x, a_w, 512);
  kgather<<<dim3(512), dim3(256), 0, stream>>>(embp, x, a_p, 768);

  // layer-0 projections
  kgemm<<<dim3(512), dim3(256), 0, stream>>>(a_w, pw_l1Wih0, l1b0, xg0, 512);
  kgemm<<<dim3(512), dim3(256), 0, stream>>>(a_p, pw_f0Wih,  f0b,  xg1, 768);
  kgemm<<<dim3(512), dim3(256), 0, stream>>>(a_p, pw_r0Wih,  r0b,  xg2, 768);

  // layer-0 scans: word fwd, para fwd, para rev (rev writes cat0 cols 1000..)
  {
    ScanArgs sa;
    sa.d[0] = LstmDesc{xg0, l1Whh0, h_w0, 1024, 0, 0};
    sa.d[1] = LstmDesc{xg1, f0Whh,  cat0, 2048, 0, 0};
    sa.d[2] = LstmDesc{xg2, r0Whh,  cat0, 2048, 1000, 1};
    sa.bar = barB;
    kscan<<<dim3(189), dim3(256), 0, stream>>>(sa);
  }

  // layer-1 projections (A = layer-0 h sequences)
  kgemm<<<dim3(512), dim3(256), 0, stream>>>(h_w0, pw_l1Wih1, l1b1, xg0, 1024);
  kgemm<<<dim3(512), dim3(256), 0, stream>>>(cat0, pw_f1Wih,  f1b,  xg1, 2048);
  kgemm<<<dim3(512), dim3(256), 0, stream>>>(cat0, pw_r1Wih,  r1b,  xg2, 2048);

  // layer-1 scans: word fwd + para fwd (para rev needs only step 0 -> kfinal)
  {
    ScanArgs sa;
    sa.d[0] = LstmDesc{xg0, l1Whh1, h_w1,  1024, 0, 0};
    sa.d[1] = LstmDesc{xg1, f1Whh,  h_pf1, 1024, 0, 0};
    sa.d[2] = LstmDesc{nullptr, nullptr, nullptr, 1024, 0, 0};
    sa.bar = barD;
    kscan<<<dim3(126), dim3(256), 0, stream>>>(sa);
  }

  kfinal<<<dim3(1), dim3(256), 0, stream>>>(h_w1, h_pf1, xg2,
                                            w1, b1, w2, b2, wc, bc, out);
}

// Round 3
// 2723.660 us; speedup vs baseline: 3.8139x; 1.1695x over previous
//
#include <hip/hip_runtime.h>
#include <stdint.h>
#include <math.h>

// ---------------------------------------------------------------------------
// StoryJudger2: word branch (2x LSTM H=1000) + paragraph branch (2x biLSTM)
// B=8, S=256, V=50257, E=512, P=768, H=1000.
//
// Strategy:
//  - Input projections xg = A @ Wih^T + b as bf16 MFMA GEMMs (f32 out).
//  - Recurrent scans: persistent kernel, 32 WGs x 512 thr per LSTM, Whh
//    register-resident as MFMA B-fragments; per-step h broadcast via RELAXED
//    AGENT-SCOPE atomics (no cache-wide fences) and a flag-array barrier
//    (epoch stores + parallel poll -- no RMW convoy).
//  - para reverse layer-1 only needs step 0 (h0=c0=0) -> closed form in final.
// ---------------------------------------------------------------------------

typedef __attribute__((ext_vector_type(8))) short short8;
typedef __attribute__((ext_vector_type(4))) float f32x4;
typedef __attribute__((ext_vector_type(4))) unsigned int u32x4;
typedef unsigned long long ull;

#define BB 8
#define SS 256
#define MM (BB*SS)     // 2048 token rows
#define HH 1000
#define GG 4000        // 4*H gate dim
#define NP 4096        // padded gate dim (GEMM N)
#define HP 1024        // padded hidden dim (K for recurrent mfma)

__device__ __forceinline__ unsigned short f2bf(float f){
  unsigned u = __builtin_bit_cast(unsigned, f);
  unsigned r = u + 0x7fffu + ((u >> 16) & 1u);     // RNE
  return (unsigned short)(r >> 16);
}
__device__ __forceinline__ float bf2f(unsigned short s){
  unsigned u = ((unsigned)s) << 16;
  return __builtin_bit_cast(float, u);
}
// precise (kfinal, one-shot)
__device__ __forceinline__ float sigf(float x){ return 1.0f / (1.0f + expf(-x)); }
// fast (scan inner loop): v_exp-based, ~1e-6 rel err << bf16 rounding
__device__ __forceinline__ float fsig(float x){ return 1.0f / (1.0f + __expf(-x)); }
__device__ __forceinline__ float ftanh(float x){
  const float e = __expf(-2.0f * fabsf(x));
  const float r = (1.0f - e) / (1.0f + e);
  return x < 0.0f ? -r : r;
}

__device__ __forceinline__ void async_copy16(const void* g, void* l){
  __builtin_amdgcn_global_load_lds(
      (const __attribute__((address_space(1))) unsigned int*)g,
      (__attribute__((address_space(3))) unsigned int*)l, 16, 0, 0);
}

// ---------------------------------------------------------------- prep ------
__global__ void kzero(unsigned int* __restrict__ p, size_t nwords){
  size_t stride = (size_t)gridDim.x * blockDim.x;
  for (size_t i = (size_t)blockIdx.x*blockDim.x + threadIdx.x; i < nwords; i += stride)
    p[i] = 0u;
}

__global__ void kpadw(const float* __restrict__ src, unsigned short* __restrict__ dst,
                      int K, int Kpad){
  size_t total = (size_t)NP * Kpad;
  size_t stride = (size_t)gridDim.x * blockDim.x;
  for (size_t i = (size_t)blockIdx.x*blockDim.x + threadIdx.x; i < total; i += stride){
    int nrow = (int)(i / Kpad);
    int k    = (int)(i % Kpad);
    float v = (nrow < GG && k < K) ? src[(size_t)nrow*K + k] : 0.0f;
    dst[i] = f2bf(v);
  }
}

__global__ void kgather(const float* __restrict__ emb, const int* __restrict__ x,
                        unsigned short* __restrict__ dst, int E){
  size_t total = (size_t)MM * E;
  size_t stride = (size_t)gridDim.x * blockDim.x;
  for (size_t i = (size_t)blockIdx.x*blockDim.x + threadIdx.x; i < total; i += stride){
    size_t m = i / E, e = i % E;
    dst[i] = f2bf(emb[(size_t)x[m]*E + e]);
  }
}

// ---------------------------------------------------------------- GEMM ------
__launch_bounds__(256, 2)
__global__ void kgemm(const unsigned short* __restrict__ A,
                      const unsigned short* __restrict__ W,
                      const float* __restrict__ bias,
                      float* __restrict__ out, int Kpad){
  __shared__ __align__(16) unsigned short ldsA[128*64];
  __shared__ __align__(16) unsigned short ldsB[128*64];
  const int tid = threadIdx.x;
  const int w = tid >> 6, l = tid & 63;
  const int wr = w >> 1, wc = w & 1;
  const int tm = blockIdx.x & 15, tn = blockIdx.x >> 4;
  const size_t Kb = (size_t)Kpad * 2;
  const int nk = Kpad >> 6;

  f32x4 acc[4][4];
#pragma unroll
  for (int a = 0; a < 4; ++a)
#pragma unroll
    for (int b = 0; b < 4; ++b) acc[a][b] = (f32x4){0.f,0.f,0.f,0.f};

  for (int kt = 0; kt < nk; ++kt){
#pragma unroll
    for (int c = 0; c < 4; ++c){
      const int chunk = c*4 + w;
      const int flat = chunk*1024 + l*16;
      const int row = flat >> 7;
      const int off = flat & 127;
      const int soff = off ^ ((row & 7) << 4);
      async_copy16((const char*)A + (size_t)(tm*128+row)*Kb + (size_t)kt*128 + soff,
                   (char*)ldsA + chunk*1024);
      async_copy16((const char*)W + (size_t)(tn*128+row)*Kb + (size_t)kt*128 + soff,
                   (char*)ldsB + chunk*1024);
    }
    asm volatile("s_waitcnt vmcnt(0)" ::: "memory");
    __syncthreads();

#pragma unroll
    for (int ks = 0; ks < 2; ++ks){
      short8 af[4], bf[4];
#pragma unroll
      for (int mf = 0; mf < 4; ++mf){
        const int row = wr*64 + mf*16 + (l & 15);
        const int off = ((ks*32 + (l>>4)*8)*2) ^ ((row & 7) << 4);
        af[mf] = *(const short8*)((const char*)ldsA + row*128 + off);
      }
#pragma unroll
      for (int nf = 0; nf < 4; ++nf){
        const int row = wc*64 + nf*16 + (l & 15);
        const int off = ((ks*32 + (l>>4)*8)*2) ^ ((row & 7) << 4);
        bf[nf] = *(const short8*)((const char*)ldsB + row*128 + off);
      }
#pragma unroll
      for (int mf = 0; mf < 4; ++mf)
#pragma unroll
        for (int nf = 0; nf < 4; ++nf)
          acc[mf][nf] = __builtin_amdgcn_mfma_f32_16x16x32_bf16(
              af[mf], bf[nf], acc[mf][nf], 0, 0, 0);
    }
    __syncthreads();
  }

#pragma unroll
  for (int nf = 0; nf < 4; ++nf){
    const int n = tn*128 + wc*64 + nf*16 + (l & 15);
    if (n < GG){
      const float bv = bias[n];
#pragma unroll
      for (int mf = 0; mf < 4; ++mf){
#pragma unroll
        for (int q = 0; q < 4; ++q){
          const int m = tm*128 + wr*64 + mf*16 + (l>>4)*4 + q;
          out[(size_t)m*GG + n] = acc[mf][nf][q] + bv;
        }
      }
    }
  }
}

// ---------------------------------------------------------------- scan ------
struct LstmDesc {
  const float* xg;          // [2048][4000] f32 (bias included)
  const float* whh;         // [4000][1000] f32
  unsigned short* hbuf;     // bf16 h sequence buffer (also feedback source)
  int hstride;              // row stride in elems (1024 or 2048)
  int joff;                 // column offset in hbuf
  int rev;                  // reversed scan
};
struct ScanArgs {
  LstmDesc d[3];
  unsigned int* bar;        // flags: [lstm][64] u32 (32 used), pre-zeroed
};

// 32 WGs x 512 threads (8 waves) per LSTM; each wave owns 4 hidden units x
// 4 gates (16 MFMA cols), Whh slice in 128 weight-VGPRs for all 256 steps.
// Barrier: epoch-store flag array + parallel 32-lane poll (no RMW convoy).
__launch_bounds__(512, 2)
__global__ void kscan(ScanArgs args){
  __shared__ __align__(16) unsigned short h_lds[8*HP];  // swizzled [8][1024] bf16
  __shared__ float ex[8][128];                          // per-wave gate exchange
  __shared__ unsigned short exh[8][32];                 // per-wave packed h out
  const int tid = threadIdx.x;
  const int wv = tid >> 6, l = tid & 63;
  const int lstm = blockIdx.x >> 5, slice = blockIdx.x & 31;
  const LstmDesc D = args.d[lstm];
  unsigned int* flags = args.bar + lstm * 64;

  const int col = l & 15, g4 = l >> 4;
  const int gate = col >> 2, jl = col & 3;
  const int j = slice*32 + wv*4 + jl;          // hidden unit for this mfma col
  const int n = gate*HH + j;                   // gate-column in [0,4000)
  const bool jv = (j < HH);

  // ---- one-time: load Whh B-fragments (lane holds B[k][col]=Whh[n][k]) ----
  short8 wf[32];
#pragma unroll
  for (int ks = 0; ks < 32; ++ks){
    short8 v = (short8){0,0,0,0,0,0,0,0};
    const int kb = ks*32 + g4*8;
    if (jv && kb < HH){
      const float* s = D.whh + (size_t)n*HH + kb;
#pragma unroll
      for (int i = 0; i < 8; ++i) v[i] = (short)f2bf(s[i]);
    }
    wf[ks] = v;
  }

  const int arow = l & 15;                     // A-fragment batch row
  const bool av = arow < 8;
  const int aswz = (arow & 7) << 4;
  float c_reg = 0.f;                           // cell state (lanes 0..31)
  const int ub = l & 7, ujl = (l >> 3) & 3;
  const int ubase = slice*32 + wv*4;           // first unit of this wave
  const bool sv = (ubase < HH);                // wave's 4 units valid (4|1000)

  // xg for t=0 (f32, bias included): 4 batch rows per lane
  float xgv[4] = {0.f,0.f,0.f,0.f};
  {
    const int pos0 = D.rev ? (SS-1) : 0;
    if (g4 < 2 && jv){
#pragma unroll
      for (int q = 0; q < 4; ++q)
        xgv[q] = D.xg[(size_t)((g4*4+q)*SS + pos0)*GG + n];
    }
  }

  for (int t = 0; t < SS; ++t){
    const int pos  = D.rev ? (SS-1 - t) : t;
    const int ppos = D.rev ? (pos + 1) : (pos - 1);

    // stage h_prev (8 x 1024 bf16) into LDS, XOR-swizzled rows
    if (t == 0){
#pragma unroll
      for (int cc = 0; cc < 2; ++cc)
        *(u32x4*)((char*)h_lds + (cc*512 + tid)*16) = (u32x4){0u,0u,0u,0u};
    } else {
#pragma unroll
      for (int cc = 0; cc < 4; ++cc){
        const int f8 = cc*512 + tid;
        const int fb = f8*8;                   // byte offset in 16KB h block
        const int hr = fb >> 11;               // batch row 0..7
        const int off = fb & 2047;
        const ull* src = (const ull*)
            ((const char*)D.hbuf + ((size_t)(hr*SS + ppos)*D.hstride + D.joff)*2 + off);
        const ull v = __hip_atomic_load(src, __ATOMIC_RELAXED, __HIP_MEMORY_SCOPE_AGENT);
        *(ull*)((char*)h_lds + hr*2048 + (off ^ ((hr & 7) << 4))) = v;
      }
    }
    __syncthreads();

    // gates = h_prev @ Whh^T  (K=1024, two independent 16-mfma chains)
    f32x4 a0 = (f32x4){0.f,0.f,0.f,0.f};
    f32x4 a1 = (f32x4){0.f,0.f,0.f,0.f};
#pragma unroll
    for (int ks = 0; ks < 16; ++ks){
      const int off0 = (((2*ks  )*64) | (g4*16)) ^ aswz;
      const int off1 = (((2*ks+1)*64) | (g4*16)) ^ aswz;
      short8 s0 = av ? *(const short8*)((const char*)h_lds + arow*2048 + off0)
                     : (short8){0,0,0,0,0,0,0,0};
      short8 s1 = av ? *(const short8*)((const char*)h_lds + arow*2048 + off1)
                     : (short8){0,0,0,0,0,0,0,0};
      a0 = __builtin_amdgcn_mfma_f32_16x16x32_bf16(s0, wf[2*ks  ], a0, 0, 0, 0);
      a1 = __builtin_amdgcn_mfma_f32_16x16x32_bf16(s1, wf[2*ks+1], a1, 0, 0, 0);
    }

    // exchange i/f/g/o within wave (wave-local LDS: no block barrier needed)
    if (g4 < 2){
#pragma unroll
      for (int q = 0; q < 4; ++q)
        ex[wv][(jl*4 + gate)*8 + (g4*4 + q)] = a0[q] + a1[q] + xgv[q];
    }

    if (l < 32){
      const float iv = ex[wv][(ujl*4 + 0)*8 + ub];
      const float fv = ex[wv][(ujl*4 + 1)*8 + ub];
      const float gv = ex[wv][(ujl*4 + 2)*8 + ub];
      const float ov = ex[wv][(ujl*4 + 3)*8 + ub];
      c_reg = fsig(fv)*c_reg + fsig(iv)*ftanh(gv);
      const float h = fsig(ov)*ftanh(c_reg);
      exh[wv][ub*4 + ujl] = f2bf(h);
    }
    // packed 8B h store: lane b<8 stores this wave's 4 units for batch b
    if (l < 8 && sv){
      const ull hv = *(const ull*)&exh[wv][l*4];
      ull* dst = (ull*)&D.hbuf[(size_t)(l*SS + pos)*D.hstride + D.joff + ubase];
      __hip_atomic_store(dst, hv, __ATOMIC_RELAXED, __HIP_MEMORY_SCOPE_AGENT);
    }

    // prefetch xg for t+1 (latency hides under the barrier)
    float xgn[4] = {0.f,0.f,0.f,0.f};
    if (t+1 < SS && g4 < 2 && jv){
      const int npos = D.rev ? (pos - 1) : (pos + 1);
#pragma unroll
      for (int q = 0; q < 4; ++q)
        xgn[q] = D.xg[(size_t)((g4*4+q)*SS + npos)*GG + n];
    }

    // __syncthreads drains vmcnt(0) per wave -> all h stores complete at the
    // coherence point before the flag store below.
    __syncthreads();

    if (wv == 0){
      const unsigned tgt = (unsigned)(t + 1);
      if (l == 0)
        __hip_atomic_store(&flags[slice], tgt, __ATOMIC_RELAXED, __HIP_MEMORY_SCOPE_AGENT);
      unsigned vflag = tgt;
      for (;;){
        if (l < 32)
          vflag = __hip_atomic_load(&flags[l], __ATOMIC_RELAXED, __HIP_MEMORY_SCOPE_AGENT);
        if (__all((int)(vflag >= tgt))) break;
        __builtin_amdgcn_s_sleep(1);
      }
    }
    __syncthreads();
    asm volatile("" ::: "memory");

#pragma unroll
    for (int q = 0; q < 4; ++q) xgv[q] = xgn[q];
  }
}

// --------------------------------------------------------------- final ------
__global__ void kfinal(const unsigned short* __restrict__ hw1,
                       const unsigned short* __restrict__ hpf1,
                       const float* __restrict__ xgr1,
                       const float* __restrict__ w1, const float* __restrict__ b1,
                       const float* __restrict__ w2, const float* __restrict__ b2,
                       const float* __restrict__ wc, const float* __restrict__ bc,
                       float* __restrict__ out){
  __shared__ float red[256];
  const int tid = threadIdx.x;
  for (int b = 0; b < BB; ++b){
    const size_t r = (size_t)(b*SS + (SS-1));
    float ps = 0.f, wsm = 0.f;
    for (int j = tid; j < HH; j += 256){
      ps  += bf2f(hpf1[r*1024 + j]) * w2[j];
      // para reverse layer-1, step 0 (h0=c0=0): closed form from xg
      const float iv = xgr1[r*GG + j];
      const float gv = xgr1[r*GG + 2000 + j];
      const float ov = xgr1[r*GG + 3000 + j];
      const float cc = sigf(iv)*tanhf(gv);
      ps  += sigf(ov)*tanhf(cc) * w2[HH + j];
      wsm += bf2f(hw1[r*1024 + j]) * w1[j];
    }
    red[tid] = ps; __syncthreads();
    for (int s = 128; s > 0; s >>= 1){ if (tid < s) red[tid] += red[tid+s]; __syncthreads(); }
    const float PS = red[0]; __syncthreads();
    red[tid] = wsm; __syncthreads();
    for (int s = 128; s > 0; s >>= 1){ if (tid < s) red[tid] += red[tid+s]; __syncthreads(); }
    const float WS = red[0]; __syncthreads();
    if (tid == 0)
      out[b] = wc[0]*(PS + b2[0]) + wc[1]*(WS + b1[0]) + bc[0];
    __syncthreads();
  }
}

// --------------------------------------------------------------- host -------
extern "C" void kernel_launch(void* const* d_in, const int* in_sizes, int n_in,
                              void* d_out, int out_size, void* d_ws, size_t ws_size,
                              hipStream_t stream){
  const int*   x      = (const int*)  d_in[0];
  const float* embw   = (const float*)d_in[1];
  const float* embp   = (const float*)d_in[2];
  const float* l1Wih0 = (const float*)d_in[3];
  const float* l1Whh0 = (const float*)d_in[4];
  const float* l1b0   = (const float*)d_in[5];
  const float* l1Wih1 = (const float*)d_in[6];
  const float* l1Whh1 = (const float*)d_in[7];
  const float* l1b1   = (const float*)d_in[8];
  const float* f0Wih  = (const float*)d_in[9];
  const float* f0Whh  = (const float*)d_in[10];
  const float* f0b    = (const float*)d_in[11];
  const float* r0Wih  = (const float*)d_in[12];
  const float* r0Whh  = (const float*)d_in[13];
  const float* r0b    = (const float*)d_in[14];
  const float* f1Wih  = (const float*)d_in[15];
  const float* f1Whh  = (const float*)d_in[16];
  const float* f1b    = (const float*)d_in[17];
  const float* r1Wih  = (const float*)d_in[18];
  const float* r1Whh  = (const float*)d_in[19];
  const float* r1b    = (const float*)d_in[20];
  const float* w1     = (const float*)d_in[21];
  const float* b1     = (const float*)d_in[22];
  const float* w2     = (const float*)d_in[23];
  const float* b2     = (const float*)d_in[24];
  const float* wc     = (const float*)d_in[25];
  const float* bc     = (const float*)d_in[26];
  float* out = (float*)d_out;
  (void)in_sizes; (void)n_in; (void)out_size; (void)ws_size;

  char* ws = (char*)d_ws;
  size_t off = 0;
  auto alloc = [&](size_t bytes)->char*{
    char* p = ws + off;
    off += (bytes + 255) & ~(size_t)255;
    return p;
  };
  // padded bf16 Wih copies [4096][Kpad]
  unsigned short* pw_l1Wih0 = (unsigned short*)alloc((size_t)NP*512*2);
  unsigned short* pw_f0Wih  = (unsigned short*)alloc((size_t)NP*768*2);
  unsigned short* pw_r0Wih  = (unsigned short*)alloc((size_t)NP*768*2);
  unsigned short* pw_l1Wih1 = (unsigned short*)alloc((size_t)NP*1024*2);
  unsigned short* pw_f1Wih  = (unsigned short*)alloc((size_t)NP*2048*2);
  unsigned short* pw_r1Wih  = (unsigned short*)alloc((size_t)NP*2048*2);
  // gathered embeddings (bf16)
  unsigned short* a_w = (unsigned short*)alloc((size_t)MM*512*2);
  unsigned short* a_p = (unsigned short*)alloc((size_t)MM*768*2);
  // gate pre-activations (f32), reused across the two layers
  float* xg0 = (float*)alloc((size_t)MM*GG*4);
  float* xg1 = (float*)alloc((size_t)MM*GG*4);
  float* xg2 = (float*)alloc((size_t)MM*GG*4);
  // h sequence buffers (bf16) + barrier flags -- contiguous, zeroed per call
  char* zbase = ws + off;
  unsigned short* h_w0  = (unsigned short*)alloc((size_t)MM*1024*2);
  unsigned short* cat0  = (unsigned short*)alloc((size_t)MM*2048*2); // [fwd|rev|pad]
  unsigned short* h_w1  = (unsigned short*)alloc((size_t)MM*1024*2);
  unsigned short* h_pf1 = (unsigned short*)alloc((size_t)MM*1024*2);
  unsigned int* barB = (unsigned int*)alloc(3*64*4);
  unsigned int* barD = (unsigned int*)alloc(3*64*4);
  size_t zwords = (size_t)((ws + off) - zbase) / 4;

  kzero<<<dim3(1024), dim3(256), 0, stream>>>((unsigned int*)zbase, zwords);
  kpadw<<<dim3(1024), dim3(256), 0, stream>>>(l1Wih0, pw_l1Wih0, 512, 512);
  kpadw<<<dim3(1024), dim3(256), 0, stream>>>(f0Wih,  pw_f0Wih,  768, 768);
  kpadw<<<dim3(1024), dim3(256), 0, stream>>>(r0Wih,  pw_r0Wih,  768, 768);
  kpadw<<<dim3(1024), dim3(256), 0, stream>>>(l1Wih1, pw_l1Wih1, 1000, 1024);
  kpadw<<<dim3(1024), dim3(256), 0, stream>>>(f1Wih,  pw_f1Wih,  2000, 2048);
  kpadw<<<dim3(1024), dim3(256), 0, stream>>>(r1Wih,  pw_r1Wih,  2000, 2048);
  kgather<<<dim3(512), dim3(256), 0, stream>>>(embw, x, a_w, 512);
  kgather<<<dim3(512), dim3(256), 0, stream>>>(embp, x, a_p, 768);

  // layer-0 projections
  kgemm<<<dim3(512), dim3(256), 0, stream>>>(a_w, pw_l1Wih0, l1b0, xg0, 512);
  kgemm<<<dim3(512), dim3(256), 0, stream>>>(a_p, pw_f0Wih,  f0b,  xg1, 768);
  kgemm<<<dim3(512), dim3(256), 0, stream>>>(a_p, pw_r0Wih,  r0b,  xg2, 768);

  // layer-0 scans: word fwd, para fwd, para rev (rev writes cat0 cols 1000..)
  {
    ScanArgs sa;
    sa.d[0] = LstmDesc{xg0, l1Whh0, h_w0, 1024, 0, 0};
    sa.d[1] = LstmDesc{xg1, f0Whh,  cat0, 2048, 0, 0};
    sa.d[2] = LstmDesc{xg2, r0Whh,  cat0, 2048, 1000, 1};
    sa.bar = barB;
    kscan<<<dim3(96), dim3(512), 0, stream>>>(sa);
  }

  // layer-1 projections (A = layer-0 h sequences)
  kgemm<<<dim3(512), dim3(256), 0, stream>>>(h_w0, pw_l1Wih1, l1b1, xg0, 1024);
  kgemm<<<dim3(512), dim3(256), 0, stream>>>(cat0, pw_f1Wih,  f1b,  xg1, 2048);
  kgemm<<<dim3(512), dim3(256), 0, stream>>>(cat0, pw_r1Wih,  r1b,  xg2, 2048);

  // layer-1 scans: word fwd + para fwd (para rev needs only step 0 -> kfinal)
  {
    ScanArgs sa;
    sa.d[0] = LstmDesc{xg0, l1Whh1, h_w1,  1024, 0, 0};
    sa.d[1] = LstmDesc{xg1, f1Whh,  h_pf1, 1024, 0, 0};
    sa.d[2] = LstmDesc{nullptr, nullptr, nullptr, 1024, 0, 0};
    sa.bar = barD;
    kscan<<<dim3(64), dim3(512), 0, stream>>>(sa);
  }

  kfinal<<<dim3(1), dim3(256), 0, stream>>>(h_w1, h_pf1, xg2,
                                            w1, b1, w2, b2, wc, bc, out);
}

// Round 4
// 2185.217 us; speedup vs baseline: 4.7536x; 1.2464x over previous
//
#include <hip/hip_runtime.h>
#include <stdint.h>
#include <math.h>

// ---------------------------------------------------------------------------
// StoryJudger2: word branch (2x LSTM H=1000) + paragraph branch (2x biLSTM)
// B=8, S=256, V=50257, E=512, P=768, H=1000.
//
// Strategy:
//  - Input projections xg = A @ Wih^T + b as bf16 MFMA GEMMs (f32 out).
//  - Recurrent scans: persistent kernel, 32 WGs x 512 thr per LSTM, Whh
//    register-resident as MFMA B-fragments. NO barrier: h is stored
//    BIT-INVERTED to a write-once position-indexed buffer; consumers poll
//    the exact words they need (0x0000 == not-written since |h|<1 never
//    inverts to 0 and slots are pre-zeroed). One __syncthreads per step
//    (double-buffered LDS h tile).
//  - h buffers hold INVERTED bf16 -> kdecode before layer-1 GEMMs; kfinal
//    decodes inline.
//  - para reverse layer-1 only needs step 0 (h0=c0=0) -> closed form in final.
// ---------------------------------------------------------------------------

typedef __attribute__((ext_vector_type(8))) short short8;
typedef __attribute__((ext_vector_type(4))) float f32x4;
typedef __attribute__((ext_vector_type(4))) unsigned int u32x4;
typedef unsigned long long ull;

#define BB 8
#define SS 256
#define MM (BB*SS)     // 2048 token rows
#define HH 1000
#define GG 4000        // 4*H gate dim
#define NP 4096        // padded gate dim (GEMM N)
#define HP 1024        // padded hidden dim (K for recurrent mfma)

__device__ __forceinline__ unsigned short f2bf(float f){
  unsigned u = __builtin_bit_cast(unsigned, f);
  unsigned r = u + 0x7fffu + ((u >> 16) & 1u);     // RNE
  return (unsigned short)(r >> 16);
}
__device__ __forceinline__ float bf2f(unsigned short s){
  unsigned u = ((unsigned)s) << 16;
  return __builtin_bit_cast(float, u);
}
// precise (kfinal, one-shot)
__device__ __forceinline__ float sigf(float x){ return 1.0f / (1.0f + expf(-x)); }
// fast (scan inner loop): v_exp-based, ~1e-6 rel err << bf16 rounding
__device__ __forceinline__ float fsig(float x){ return 1.0f / (1.0f + __expf(-x)); }
__device__ __forceinline__ float ftanh(float x){
  const float e = __expf(-2.0f * fabsf(x));
  const float r = (1.0f - e) / (1.0f + e);
  return x < 0.0f ? -r : r;
}
// all four u16 fields nonzero?
__device__ __forceinline__ bool valid4(ull v){
  return (v & 0xffffull) && (v & 0xffff0000ull) &&
         (v & 0xffff00000000ull) && (v >> 48);
}

__device__ __forceinline__ void async_copy16(const void* g, void* l){
  __builtin_amdgcn_global_load_lds(
      (const __attribute__((address_space(1))) unsigned int*)g,
      (__attribute__((address_space(3))) unsigned int*)l, 16, 0, 0);
}

// ---------------------------------------------------------------- prep ------
__global__ void kzero(unsigned int* __restrict__ p, size_t nwords){
  size_t stride = (size_t)gridDim.x * blockDim.x;
  for (size_t i = (size_t)blockIdx.x*blockDim.x + threadIdx.x; i < nwords; i += stride)
    p[i] = 0u;
}

__global__ void kpadw(const float* __restrict__ src, unsigned short* __restrict__ dst,
                      int K, int Kpad){
  size_t total = (size_t)NP * Kpad;
  size_t stride = (size_t)gridDim.x * blockDim.x;
  for (size_t i = (size_t)blockIdx.x*blockDim.x + threadIdx.x; i < total; i += stride){
    int nrow = (int)(i / Kpad);
    int k    = (int)(i % Kpad);
    float v = (nrow < GG && k < K) ? src[(size_t)nrow*K + k] : 0.0f;
    dst[i] = f2bf(v);
  }
}

__global__ void kgather(const float* __restrict__ emb, const int* __restrict__ x,
                        unsigned short* __restrict__ dst, int E){
  size_t total = (size_t)MM * E;
  size_t stride = (size_t)gridDim.x * blockDim.x;
  for (size_t i = (size_t)blockIdx.x*blockDim.x + threadIdx.x; i < total; i += stride){
    size_t m = i / E, e = i % E;
    dst[i] = f2bf(emb[(size_t)x[m]*E + e]);
  }
}

// in-place decode of inverted-h buffers: per u16, x ? ~x : 0
// (never-written padding stays 0.0, not NaN)
__global__ void kdecode(ull* __restrict__ p, size_t n64){
  size_t stride = (size_t)gridDim.x * blockDim.x;
  for (size_t i = (size_t)blockIdx.x*blockDim.x + threadIdx.x; i < n64; i += stride){
    const ull v = p[i];
    ull m = 0;
    if (v & 0xffffull)          m |= 0xffffull;
    if (v & 0xffff0000ull)      m |= 0xffff0000ull;
    if (v & 0xffff00000000ull)  m |= 0xffff00000000ull;
    if (v >> 48)                m |= 0xffff000000000000ull;
    p[i] = (~v) & m;
  }
}

// ---------------------------------------------------------------- GEMM ------
__launch_bounds__(256, 2)
__global__ void kgemm(const unsigned short* __restrict__ A,
                      const unsigned short* __restrict__ W,
                      const float* __restrict__ bias,
                      float* __restrict__ out, int Kpad){
  __shared__ __align__(16) unsigned short ldsA[128*64];
  __shared__ __align__(16) unsigned short ldsB[128*64];
  const int tid = threadIdx.x;
  const int w = tid >> 6, l = tid & 63;
  const int wr = w >> 1, wc = w & 1;
  const int tm = blockIdx.x & 15, tn = blockIdx.x >> 4;
  const size_t Kb = (size_t)Kpad * 2;
  const int nk = Kpad >> 6;

  f32x4 acc[4][4];
#pragma unroll
  for (int a = 0; a < 4; ++a)
#pragma unroll
    for (int b = 0; b < 4; ++b) acc[a][b] = (f32x4){0.f,0.f,0.f,0.f};

  for (int kt = 0; kt < nk; ++kt){
#pragma unroll
    for (int c = 0; c < 4; ++c){
      const int chunk = c*4 + w;
      const int flat = chunk*1024 + l*16;
      const int row = flat >> 7;
      const int off = flat & 127;
      const int soff = off ^ ((row & 7) << 4);
      async_copy16((const char*)A + (size_t)(tm*128+row)*Kb + (size_t)kt*128 + soff,
                   (char*)ldsA + chunk*1024);
      async_copy16((const char*)W + (size_t)(tn*128+row)*Kb + (size_t)kt*128 + soff,
                   (char*)ldsB + chunk*1024);
    }
    asm volatile("s_waitcnt vmcnt(0)" ::: "memory");
    __syncthreads();

#pragma unroll
    for (int ks = 0; ks < 2; ++ks){
      short8 af[4], bf[4];
#pragma unroll
      for (int mf = 0; mf < 4; ++mf){
        const int row = wr*64 + mf*16 + (l & 15);
        const int off = ((ks*32 + (l>>4)*8)*2) ^ ((row & 7) << 4);
        af[mf] = *(const short8*)((const char*)ldsA + row*128 + off);
      }
#pragma unroll
      for (int nf = 0; nf < 4; ++nf){
        const int row = wc*64 + nf*16 + (l & 15);
        const int off = ((ks*32 + (l>>4)*8)*2) ^ ((row & 7) << 4);
        bf[nf] = *(const short8*)((const char*)ldsB + row*128 + off);
      }
#pragma unroll
      for (int mf = 0; mf < 4; ++mf)
#pragma unroll
        for (int nf = 0; nf < 4; ++nf)
          acc[mf][nf] = __builtin_amdgcn_mfma_f32_16x16x32_bf16(
              af[mf], bf[nf], acc[mf][nf], 0, 0, 0);
    }
    __syncthreads();
  }

#pragma unroll
  for (int nf = 0; nf < 4; ++nf){
    const int n = tn*128 + wc*64 + nf*16 + (l & 15);
    if (n < GG){
      const float bv = bias[n];
#pragma unroll
      for (int mf = 0; mf < 4; ++mf){
#pragma unroll
        for (int q = 0; q < 4; ++q){
          const int m = tm*128 + wr*64 + mf*16 + (l>>4)*4 + q;
          out[(size_t)m*GG + n] = acc[mf][nf][q] + bv;
        }
      }
    }
  }
}

// ---------------------------------------------------------------- scan ------
struct LstmDesc {
  const float* xg;          // [2048][4000] f32 (bias included)
  const float* whh;         // [4000][1000] f32
  unsigned short* hbuf;     // INVERTED bf16 h sequence buffer (write-once/slot)
  int hstride;              // row stride in elems (1024 or 2048)
  int joff;                 // column offset in hbuf
  int rev;                  // reversed scan
};
struct ScanArgs {
  LstmDesc d[3];
};

// 32 WGs x 512 threads (8 waves) per LSTM; each wave owns 4 hidden units x
// 4 gates (16 MFMA cols), Whh slice register-resident for all 256 steps.
// Sync: dataflow poll on inverted h words; one __syncthreads per step.
__launch_bounds__(512, 2)
__global__ void kscan(ScanArgs args){
  __shared__ __align__(16) unsigned short h_lds[2][8][HP];  // double-buffered
  __shared__ float ex[8][128];                              // per-wave gates
  __shared__ unsigned short exh[8][32];                     // per-wave h out
  const int tid = threadIdx.x;
  const int wv = tid >> 6, l = tid & 63;
  const int lstm = blockIdx.x >> 5, slice = blockIdx.x & 31;
  const LstmDesc D = args.d[lstm];

  const int col = l & 15, g4 = l >> 4;
  const int gate = col >> 2, jl = col & 3;
  const int j = slice*32 + wv*4 + jl;          // hidden unit for this mfma col
  const int n = gate*HH + j;                   // gate-column in [0,4000)
  const bool jv = (j < HH);

  // ---- one-time: load Whh B-fragments (lane holds B[k][col]=Whh[n][k]) ----
  short8 wf[32];
#pragma unroll
  for (int ks = 0; ks < 32; ++ks){
    short8 v = (short8){0,0,0,0,0,0,0,0};
    const int kb = ks*32 + g4*8;
    if (jv && kb < HH){
      const float* s = D.whh + (size_t)n*HH + kb;
#pragma unroll
      for (int i = 0; i < 8; ++i) v[i] = (short)f2bf(s[i]);
    }
    wf[ks] = v;
  }

  // per-thread staging-chunk constants (4 x 8B covers 16KB h tile)
  int chr_[4], coff_[4], ldso_[4];
  bool cneed_[4];
#pragma unroll
  for (int cc = 0; cc < 4; ++cc){
    const int fb = (cc*512 + tid) * 8;         // byte in 16KB tile
    chr_[cc]  = fb >> 11;                      // batch row 0..7
    coff_[cc] = fb & 2047;                     // byte within row window
    cneed_[cc] = (coff_[cc] < 2000);           // col < 1000 => written
    ldso_[cc] = chr_[cc]*2048 + (coff_[cc] ^ ((chr_[cc] & 7) << 4));
  }

  const int arow = l & 15;                     // A-fragment batch row
  const bool av = arow < 8;
  const int aswz = (arow & 7) << 4;
  float c_reg = 0.f;                           // cell state (lanes 0..31)
  const int ub = l & 7, ujl = (l >> 3) & 3;
  const int ubase = slice*32 + wv*4;           // first unit of this wave
  const bool sv = (ubase < HH);                // wave's 4 units valid

  // xg for t=0 (f32, bias included): 4 batch rows per lane
  float xgv[4] = {0.f,0.f,0.f,0.f};
  {
    const int pos0 = D.rev ? (SS-1) : 0;
    if (g4 < 2 && jv){
#pragma unroll
      for (int q = 0; q < 4; ++q)
        xgv[q] = D.xg[(size_t)((g4*4+q)*SS + pos0)*GG + n];
    }
  }

  for (int t = 0; t < SS; ++t){
    const int pos  = D.rev ? (SS-1 - t) : t;
    const int ppos = D.rev ? (pos + 1) : (pos - 1);
    const int buf = t & 1;

    // ---- acquire h_prev by polling the inverted data words themselves ----
    ull val[4] = {0ull, 0ull, 0ull, 0ull};
    if (t > 0){
      const char* src_[4];
      unsigned pend = 0;
#pragma unroll
      for (int cc = 0; cc < 4; ++cc){
        src_[cc] = (const char*)D.hbuf
            + ((size_t)(chr_[cc]*SS + ppos)*D.hstride + D.joff)*2 + coff_[cc];
        if (cneed_[cc]) pend |= 1u << cc;
      }
      while (pend){
        ull tmp[4];
#pragma unroll
        for (int cc = 0; cc < 4; ++cc)
          if (pend & (1u << cc))
            tmp[cc] = __hip_atomic_load((const ull*)src_[cc],
                                        __ATOMIC_RELAXED, __HIP_MEMORY_SCOPE_AGENT);
#pragma unroll
        for (int cc = 0; cc < 4; ++cc)
          if ((pend & (1u << cc)) && valid4(tmp[cc])){
            val[cc] = ~tmp[cc];                // decode
            pend &= ~(1u << cc);
          }
      }
    }
#pragma unroll
    for (int cc = 0; cc < 4; ++cc)
      *(ull*)((char*)h_lds + buf*16384 + ldso_[cc]) = val[cc];
    __syncthreads();

    // gates = h_prev @ Whh^T  (K=1024, two independent 16-mfma chains)
    const char* abase = (const char*)h_lds + buf*16384 + arow*2048;
    f32x4 a0 = (f32x4){0.f,0.f,0.f,0.f};
    f32x4 a1 = (f32x4){0.f,0.f,0.f,0.f};
#pragma unroll
    for (int ks = 0; ks < 16; ++ks){
      const int off0 = (((2*ks  )*64) | (g4*16)) ^ aswz;
      const int off1 = (((2*ks+1)*64) | (g4*16)) ^ aswz;
      short8 s0 = av ? *(const short8*)(abase + off0) : (short8){0,0,0,0,0,0,0,0};
      short8 s1 = av ? *(const short8*)(abase + off1) : (short8){0,0,0,0,0,0,0,0};
      a0 = __builtin_amdgcn_mfma_f32_16x16x32_bf16(s0, wf[2*ks  ], a0, 0, 0, 0);
      a1 = __builtin_amdgcn_mfma_f32_16x16x32_bf16(s1, wf[2*ks+1], a1, 0, 0, 0);
    }

    // exchange i/f/g/o within wave (wave-local LDS: no block barrier needed)
    if (g4 < 2){
#pragma unroll
      for (int q = 0; q < 4; ++q)
        ex[wv][(jl*4 + gate)*8 + (g4*4 + q)] = a0[q] + a1[q] + xgv[q];
    }

    if (l < 32){
      const float iv = ex[wv][(ujl*4 + 0)*8 + ub];
      const float fv = ex[wv][(ujl*4 + 1)*8 + ub];
      const float gv = ex[wv][(ujl*4 + 2)*8 + ub];
      const float ov = ex[wv][(ujl*4 + 3)*8 + ub];
      c_reg = fsig(fv)*c_reg + fsig(iv)*ftanh(gv);
      const float h = fsig(ov)*ftanh(c_reg);
      exh[wv][ub*4 + ujl] = f2bf(h);
    }
    // packed 8B INVERTED h store: lane b<8 stores wave's 4 units for batch b
    // (fire-and-forget; consumers poll for all-u16-nonzero)
    if (l < 8 && sv){
      const ull hv = ~(*(const ull*)&exh[wv][l*4]);
      ull* dst = (ull*)&D.hbuf[(size_t)(l*SS + pos)*D.hstride + D.joff + ubase];
      __hip_atomic_store(dst, hv, __ATOMIC_RELAXED, __HIP_MEMORY_SCOPE_AGENT);
    }

    // prefetch xg for t+1 (latency hides under the next poll)
    float xgn[4] = {0.f,0.f,0.f,0.f};
    if (t+1 < SS && g4 < 2 && jv){
      const int npos = D.rev ? (pos - 1) : (pos + 1);
#pragma unroll
      for (int q = 0; q < 4; ++q)
        xgn[q] = D.xg[(size_t)((g4*4+q)*SS + npos)*GG + n];
    }
#pragma unroll
    for (int q = 0; q < 4; ++q) xgv[q] = xgn[q];
  }
}

// --------------------------------------------------------------- final ------
__global__ void kfinal(const unsigned short* __restrict__ hw1,
                       const unsigned short* __restrict__ hpf1,
                       const float* __restrict__ xgr1,
                       const float* __restrict__ w1, const float* __restrict__ b1,
                       const float* __restrict__ w2, const float* __restrict__ b2,
                       const float* __restrict__ wc, const float* __restrict__ bc,
                       float* __restrict__ out){
  __shared__ float red[256];
  const int tid = threadIdx.x;
  for (int b = 0; b < BB; ++b){
    const size_t r = (size_t)(b*SS + (SS-1));
    float ps = 0.f, wsm = 0.f;
    for (int j = tid; j < HH; j += 256){
      // h buffers hold inverted bf16 -> decode (x ? ~x : 0)
      unsigned short hp = hpf1[r*1024 + j];
      unsigned short hw = hw1 [r*1024 + j];
      hp = hp ? (unsigned short)~hp : (unsigned short)0;
      hw = hw ? (unsigned short)~hw : (unsigned short)0;
      ps  += bf2f(hp) * w2[j];
      // para reverse layer-1, step 0 (h0=c0=0): closed form from xg
      const float iv = xgr1[r*GG + j];
      const float gv = xgr1[r*GG + 2000 + j];
      const float ov = xgr1[r*GG + 3000 + j];
      const float cc = sigf(iv)*tanhf(gv);
      ps  += sigf(ov)*tanhf(cc) * w2[HH + j];
      wsm += bf2f(hw) * w1[j];
    }
    red[tid] = ps; __syncthreads();
    for (int s = 128; s > 0; s >>= 1){ if (tid < s) red[tid] += red[tid+s]; __syncthreads(); }
    const float PS = red[0]; __syncthreads();
    red[tid] = wsm; __syncthreads();
    for (int s = 128; s > 0; s >>= 1){ if (tid < s) red[tid] += red[tid+s]; __syncthreads(); }
    const float WS = red[0]; __syncthreads();
    if (tid == 0)
      out[b] = wc[0]*(PS + b2[0]) + wc[1]*(WS + b1[0]) + bc[0];
    __syncthreads();
  }
}

// --------------------------------------------------------------- host -------
extern "C" void kernel_launch(void* const* d_in, const int* in_sizes, int n_in,
                              void* d_out, int out_size, void* d_ws, size_t ws_size,
                              hipStream_t stream){
  const int*   x      = (const int*)  d_in[0];
  const float* embw   = (const float*)d_in[1];
  const float* embp   = (const float*)d_in[2];
  const float* l1Wih0 = (const float*)d_in[3];
  const float* l1Whh0 = (const float*)d_in[4];
  const float* l1b0   = (const float*)d_in[5];
  const float* l1Wih1 = (const float*)d_in[6];
  const float* l1Whh1 = (const float*)d_in[7];
  const float* l1b1   = (const float*)d_in[8];
  const float* f0Wih  = (const float*)d_in[9];
  const float* f0Whh  = (const float*)d_in[10];
  const float* f0b    = (const float*)d_in[11];
  const float* r0Wih  = (const float*)d_in[12];
  const float* r0Whh  = (const float*)d_in[13];
  const float* r0b    = (const float*)d_in[14];
  const float* f1Wih  = (const float*)d_in[15];
  const float* f1Whh  = (const float*)d_in[16];
  const float* f1b    = (const float*)d_in[17];
  const float* r1Wih  = (const float*)d_in[18];
  const float* r1Whh  = (const float*)d_in[19];
  const float* r1b    = (const float*)d_in[20];
  const float* w1     = (const float*)d_in[21];
  const float* b1     = (const float*)d_in[22];
  const float* w2     = (const float*)d_in[23];
  const float* b2     = (const float*)d_in[24];
  const float* wc     = (const float*)d_in[25];
  const float* bc     = (const float*)d_in[26];
  float* out = (float*)d_out;
  (void)in_sizes; (void)n_in; (void)out_size; (void)ws_size;

  char* ws = (char*)d_ws;
  size_t off = 0;
  auto alloc = [&](size_t bytes)->char*{
    char* p = ws + off;
    off += (bytes + 255) & ~(size_t)255;
    return p;
  };
  // padded bf16 Wih copies [4096][Kpad]
  unsigned short* pw_l1Wih0 = (unsigned short*)alloc((size_t)NP*512*2);
  unsigned short* pw_f0Wih  = (unsigned short*)alloc((size_t)NP*768*2);
  unsigned short* pw_r0Wih  = (unsigned short*)alloc((size_t)NP*768*2);
  unsigned short* pw_l1Wih1 = (unsigned short*)alloc((size_t)NP*1024*2);
  unsigned short* pw_f1Wih  = (unsigned short*)alloc((size_t)NP*2048*2);
  unsigned short* pw_r1Wih  = (unsigned short*)alloc((size_t)NP*2048*2);
  // gathered embeddings (bf16)
  unsigned short* a_w = (unsigned short*)alloc((size_t)MM*512*2);
  unsigned short* a_p = (unsigned short*)alloc((size_t)MM*768*2);
  // gate pre-activations (f32), reused across the two layers
  float* xg0 = (float*)alloc((size_t)MM*GG*4);
  float* xg1 = (float*)alloc((size_t)MM*GG*4);
  float* xg2 = (float*)alloc((size_t)MM*GG*4);
  // h sequence buffers (inverted bf16) -- contiguous, zeroed per call
  char* zbase = ws + off;
  unsigned short* h_w0  = (unsigned short*)alloc((size_t)MM*1024*2);
  unsigned short* cat0  = (unsigned short*)alloc((size_t)MM*2048*2); // [fwd|rev|pad]
  unsigned short* h_w1  = (unsigned short*)alloc((size_t)MM*1024*2);
  unsigned short* h_pf1 = (unsigned short*)alloc((size_t)MM*1024*2);
  size_t zwords = (size_t)((ws + off) - zbase) / 4;

  kzero<<<dim3(1024), dim3(256), 0, stream>>>((unsigned int*)zbase, zwords);
  kpadw<<<dim3(1024), dim3(256), 0, stream>>>(l1Wih0, pw_l1Wih0, 512, 512);
  kpadw<<<dim3(1024), dim3(256), 0, stream>>>(f0Wih,  pw_f0Wih,  768, 768);
  kpadw<<<dim3(1024), dim3(256), 0, stream>>>(r0Wih,  pw_r0Wih,  768, 768);
  kpadw<<<dim3(1024), dim3(256), 0, stream>>>(l1Wih1, pw_l1Wih1, 1000, 1024);
  kpadw<<<dim3(1024), dim3(256), 0, stream>>>(f1Wih,  pw_f1Wih,  2000, 2048);
  kpadw<<<dim3(1024), dim3(256), 0, stream>>>(r1Wih,  pw_r1Wih,  2000, 2048);
  kgather<<<dim3(512), dim3(256), 0, stream>>>(embw, x, a_w, 512);
  kgather<<<dim3(512), dim3(256), 0, stream>>>(embp, x, a_p, 768);

  // layer-0 projections
  kgemm<<<dim3(512), dim3(256), 0, stream>>>(a_w, pw_l1Wih0, l1b0, xg0, 512);
  kgemm<<<dim3(512), dim3(256), 0, stream>>>(a_p, pw_f0Wih,  f0b,  xg1, 768);
  kgemm<<<dim3(512), dim3(256), 0, stream>>>(a_p, pw_r0Wih,  r0b,  xg2, 768);

  // layer-0 scans: word fwd, para fwd, para rev (rev writes cat0 cols 1000..)
  {
    ScanArgs sa;
    sa.d[0] = LstmDesc{xg0, l1Whh0, h_w0, 1024, 0, 0};
    sa.d[1] = LstmDesc{xg1, f0Whh,  cat0, 2048, 0, 0};
    sa.d[2] = LstmDesc{xg2, r0Whh,  cat0, 2048, 1000, 1};
    kscan<<<dim3(96), dim3(512), 0, stream>>>(sa);
  }

  // decode inverted h (h_w0 + cat0 are contiguous) before layer-1 GEMMs
  kdecode<<<dim3(2048), dim3(256), 0, stream>>>(
      (ull*)h_w0, ((size_t)MM*1024 + (size_t)MM*2048) / 4);

  // layer-1 projections (A = layer-0 h sequences, decoded)
  kgemm<<<dim3(512), dim3(256), 0, stream>>>(h_w0, pw_l1Wih1, l1b1, xg0, 1024);
  kgemm<<<dim3(512), dim3(256), 0, stream>>>(cat0, pw_f1Wih,  f1b,  xg1, 2048);
  kgemm<<<dim3(512), dim3(256), 0, stream>>>(cat0, pw_r1Wih,  r1b,  xg2, 2048);

  // layer-1 scans: word fwd + para fwd (para rev needs only step 0 -> kfinal)
  {
    ScanArgs sa;
    sa.d[0] = LstmDesc{xg0, l1Whh1, h_w1,  1024, 0, 0};
    sa.d[1] = LstmDesc{xg1, f1Whh,  h_pf1, 1024, 0, 0};
    sa.d[2] = LstmDesc{nullptr, nullptr, nullptr, 1024, 0, 0};
    kscan<<<dim3(64), dim3(512), 0, stream>>>(sa);
  }

  kfinal<<<dim3(1), dim3(256), 0, stream>>>(h_w1, h_pf1, xg2,
                                            w1, b1, w2, b2, wc, bc, out);
}